// Round 4
// baseline (4485.109 us; speedup 1.0000x reference)
//
#include <hip/hip_runtime.h>
#include <cstdint>
#include <cstddef>

#define TLEN 512
#define BATCH 1000
#define NEV 102400
#define HID 64

__device__ __forceinline__ float fast_rcp(float x) {
#if __has_builtin(__builtin_amdgcn_rcpf)
    return __builtin_amdgcn_rcpf(x);
#else
    return 1.0f / x;
#endif
}
__device__ __forceinline__ float sigm(float x) { return fast_rcp(1.0f + __expf(-x)); }
__device__ __forceinline__ float tanh_f(float x) { return fmaf(2.0f, sigm(2.0f * x), -1.0f); }

struct Src {
    const float* num;
    const int*   cat;
    const float* tab;
    const int*   bi;
    const int*   ti;
};

// ---------------------------------------------------------------------------
// compose: W'[row][col], row = per-source [W rows..., bias row], col = Wih0 row.
// segments: ccba rows 0-8, cdtx 9-26, cust 27-52, dp 53-119, remit 120-129.
// ---------------------------------------------------------------------------
__global__ __launch_bounds__(512) void compose_kernel(
    const float* __restrict__ W0, const float* __restrict__ B0,
    const float* __restrict__ W1, const float* __restrict__ B1,
    const float* __restrict__ W2, const float* __restrict__ B2,
    const float* __restrict__ W3, const float* __restrict__ B3,
    const float* __restrict__ W4, const float* __restrict__ B4,
    const float* __restrict__ Wih, const float* __restrict__ bih,
    const float* __restrict__ bhh, float* __restrict__ wp)
{
    const int col = threadIdx.x;   // 0..511 == dir*256 + r == Wih0 row index
    const int row = blockIdx.x;    // 0..129
    const float* srcW; const float* srcB; int base, IND;
    if (row < 9)        { srcW = W0; srcB = B0; base = 0;   IND = 8;  }
    else if (row < 27)  { srcW = W1; srcB = B1; base = 9;   IND = 17; }
    else if (row < 53)  { srcW = W2; srcB = B2; base = 27;  IND = 25; }
    else if (row < 120) { srcW = W3; srcB = B3; base = 53;  IND = 66; }
    else                { srcW = W4; srcB = B4; base = 120; IND = 9;  }
    const int j = row - base;
    const float* xrow = (j < IND) ? (srcW + (size_t)j * 64) : srcB;
    const float* wr = Wih + (size_t)col * 64;
    float acc = 0.0f;
#pragma unroll
    for (int h2 = 0; h2 < 64; ++h2) acc = fmaf(xrow[h2], wr[h2], acc);
    if (j == IND) acc += bih[col] + bhh[col];
    wp[(size_t)row * 512 + col] = acc;
}

// ---------------------------------------------------------------------------
// build_lists: bucket each source's events by batch-chunk (bi/NB).
// ---------------------------------------------------------------------------
__global__ __launch_bounds__(256) void build_lists(
    Src s0, Src s1, Src s2, Src s3, Src s4,
    int NB, int chunks, int cap, int* __restrict__ cnt, int* __restrict__ evlist)
{
    int g = blockIdx.x * 256 + threadIdx.x;
    if (g >= 5 * NEV) return;
    int src = g / NEV, e = g - src * NEV;
    const int* bi = (src == 0) ? s0.bi : (src == 1) ? s1.bi :
                    (src == 2) ? s2.bi : (src == 3) ? s3.bi : s4.bi;
    int c = bi[e] / NB;
    int slot = atomicAdd(&cnt[src * chunks + c], 1);
    if (slot < cap) evlist[(size_t)(src * chunks + c) * cap + slot] = e;
}

// ---------------------------------------------------------------------------
// project: g_pre[(bi-b0)*T+ti][col] = b'[col] + sum_j x[j]*W'[j][col]
// over a dense per-(src,chunk) event list, 1-deep scalar prefetch.
// ---------------------------------------------------------------------------
template<int NNUM, int NCAT>
__device__ __forceinline__ void project_body(
    const Src s, const float* __restrict__ wp, float* __restrict__ gpre,
    const int* __restrict__ list, const int n, const int b0)
{
    constexpr int IND = NCAT * 8 + NNUM;
    constexpr int NC = NCAT > 0 ? NCAT : 1;
    const int col = threadIdx.x;
    float wcol[IND];
#pragma unroll
    for (int j = 0; j < IND; ++j) wcol[j] = wp[(size_t)j * 512 + col];
    const float bcol = wp[(size_t)IND * 512 + col];

    int i = (int)blockIdx.x;
    if (i >= n) return;
    const int stride = (int)gridDim.x;

    int ev = list[i];
    int nbi = s.bi[ev], nti = s.ti[ev];
    int ncat[NC]; float nnum[NNUM];
#pragma unroll
    for (int c = 0; c < NCAT; ++c) ncat[c] = s.cat[ev * NCAT + c];
#pragma unroll
    for (int u = 0; u < NNUM; ++u) nnum[u] = s.num[(size_t)ev * NNUM + u];

    while (true) {
        const int cbi = nbi, cti = nti;
        int ccat[NC]; float cnum[NNUM];
#pragma unroll
        for (int c = 0; c < NCAT; ++c) ccat[c] = ncat[c];
#pragma unroll
        for (int u = 0; u < NNUM; ++u) cnum[u] = nnum[u];

        const int ni = i + stride;
        if (ni < n) {
            ev = list[ni];
            nbi = s.bi[ev]; nti = s.ti[ev];
#pragma unroll
            for (int c = 0; c < NCAT; ++c) ncat[c] = s.cat[ev * NCAT + c];
#pragma unroll
            for (int u = 0; u < NNUM; ++u) nnum[u] = s.num[(size_t)ev * NNUM + u];
        }

        float acc = bcol;
#pragma unroll
        for (int c = 0; c < NCAT; ++c) {
            const float* tr = s.tab + (size_t)ccat[c] * 8;
#pragma unroll
            for (int u = 0; u < 8; ++u)
                acc = fmaf(tr[u], wcol[c * 8 + u], acc);
        }
#pragma unroll
        for (int u = 0; u < NNUM; ++u)
            acc = fmaf(cnum[u], wcol[NCAT * 8 + u], acc);

        gpre[((size_t)(cbi - b0) * TLEN + cti) * 512 + col] = acc;

        i = ni;
        if (i >= n) break;
    }
}

__global__ __launch_bounds__(512) void project_all(
    Src s0, Src s1, Src s2, Src s3, Src s4,
    const float* __restrict__ wp, float* __restrict__ gpre,
    const int* __restrict__ cnt, const int* __restrict__ evlist,
    int cap, int chunkIdx, int chunks, int b0)
{
    const int src = blockIdx.y;
    int n = cnt[src * chunks + chunkIdx];
    if (n > cap) n = cap;
    const int* list = evlist + (size_t)(src * chunks + chunkIdx) * cap;
    switch (src) {
        case 0: project_body<8, 0>(s0, wp,              gpre, list, n, b0); break;
        case 1: project_body<1, 2>(s1, wp + 9 * 512,    gpre, list, n, b0); break;
        case 2: project_body<1, 3>(s2, wp + 27 * 512,   gpre, list, n, b0); break;
        case 3: project_body<2, 8>(s3, wp + 53 * 512,   gpre, list, n, b0); break;
        default: project_body<1, 1>(s4, wp + 120 * 512, gpre, list, n, b0); break;
    }
}

// ---------------------------------------------------------------------------
// rec0: recurrence over precomputed gates for one batch-chunk.
// One wave per (b,dir); lane = cell; 2-step gate prefetch.
// ---------------------------------------------------------------------------
__global__ __launch_bounds__(256) void rec0_chunk(
    const float* __restrict__ gpre, const float* __restrict__ Whh,
    const float* __restrict__ Whr, float* __restrict__ h0,
    int b0, int nb)
{
    const int wv = threadIdx.x >> 6, lane = threadIdx.x & 63;
    const int p = blockIdx.x * 4 + wv;
    if (p >= nb * 2) return;
    const int bl = p >> 1, dir = p & 1;

    float whh4[4];
#pragma unroll
    for (int k = 0; k < 4; ++k) whh4[k] = Whh[dir * 256 + k * 64 + lane];
    const float whr = Whr[dir * HID + lane];

    const float* gb = gpre + (size_t)bl * TLEN * 512 + dir * 256 + lane;
    float* h0p = h0 + (size_t)(b0 + bl) * TLEN * 2 + dir;

    auto addr = [&](int t) -> const float* {
        int tc = t < TLEN ? t : TLEN - 1;           // clamp (value unused past end)
        int tt = dir ? (TLEN - 1 - tc) : tc;
        return gb + (size_t)tt * 512;
    };

    float A[4], B[4];
    {
        const float* pa = addr(0); const float* pb = addr(1);
#pragma unroll
        for (int k = 0; k < 4; ++k) { A[k] = pa[k * 64]; B[k] = pb[k * 64]; }
    }
    float h = 0.0f, c = 0.0f;

    for (int t = 0; t < TLEN; t += 2) {
        float C[4], D[4];
        const float* pc = addr(t + 2); const float* pd = addr(t + 3);
#pragma unroll
        for (int k = 0; k < 4; ++k) { C[k] = pc[k * 64]; D[k] = pd[k * 64]; }

        {   // step t
            float gi = fmaf(whh4[0], h, A[0]);
            float gf = fmaf(whh4[1], h, A[1]);
            float gg = fmaf(whh4[2], h, A[2]);
            float go = fmaf(whh4[3], h, A[3]);
            c = sigm(gf) * c + sigm(gi) * tanh_f(gg);
            float pp = sigm(go) * tanh_f(c) * whr;
#pragma unroll
            for (int off = 1; off < 64; off <<= 1) pp += __shfl_xor(pp, off, 64);
            h = pp;
            int tt = dir ? (TLEN - 1 - t) : t;
            if (lane == 0) h0p[(size_t)tt * 2] = h;
        }
        {   // step t+1
            float gi = fmaf(whh4[0], h, B[0]);
            float gf = fmaf(whh4[1], h, B[1]);
            float gg = fmaf(whh4[2], h, B[2]);
            float go = fmaf(whh4[3], h, B[3]);
            c = sigm(gf) * c + sigm(gi) * tanh_f(gg);
            float pp = sigm(go) * tanh_f(c) * whr;
#pragma unroll
            for (int off = 1; off < 64; off <<= 1) pp += __shfl_xor(pp, off, 64);
            h = pp;
            int tt = dir ? (TLEN - 2 - t) : (t + 1);
            if (lane == 0) h0p[(size_t)tt * 2] = h;
        }
#pragma unroll
        for (int k = 0; k < 4; ++k) { A[k] = C[k]; B[k] = D[k]; }
    }
}

// ---------------------------------------------------------------------------
// LSTM layer 1 (insz=2), one wave per (b,dir), 2-step x prefetch.
// ---------------------------------------------------------------------------
__global__ __launch_bounds__(256) void lstm1_kernel(
    const float* __restrict__ h0, const float* __restrict__ Wih,
    const float* __restrict__ Whh, const float* __restrict__ Whr,
    const float* __restrict__ bih, const float* __restrict__ bhh,
    float* __restrict__ h1)
{
    int w = threadIdx.x >> 6, lane = threadIdx.x & 63;
    int p = blockIdx.x * 4 + w;
    int b = p >> 1, dir = p & 1;

    float wi0[4], wi1[4], whh[4], bias[4];
#pragma unroll
    for (int k = 0; k < 4; ++k) {
        int r = k * 64 + lane;
        wi0[k] = Wih[(size_t)(dir * 256 + r) * 2 + 0];
        wi1[k] = Wih[(size_t)(dir * 256 + r) * 2 + 1];
        whh[k] = Whh[dir * 256 + r];
        bias[k] = bih[dir * 256 + r] + bhh[dir * 256 + r];
    }
    float whr = Whr[dir * HID + lane];
    float h = 0.0f, c = 0.0f;
    const float* hb = h0 + (size_t)b * TLEN * 2;

    auto xat = [&](int t) -> float2 {
        int tc = t < TLEN ? t : TLEN - 1;
        int tt = dir ? (TLEN - 1 - tc) : tc;
        return *(const float2*)(hb + (size_t)tt * 2);
    };

    float2 xA = xat(0), xB = xat(1);
    for (int t = 0; t < TLEN; t += 2) {
        float2 xC = xat(t + 2), xD = xat(t + 3);
        {
            float g[4];
#pragma unroll
            for (int k = 0; k < 4; ++k)
                g[k] = fmaf(whh[k], h, fmaf(wi1[k], xA.y, fmaf(wi0[k], xA.x, bias[k])));
            c = sigm(g[1]) * c + sigm(g[0]) * tanh_f(g[2]);
            float pp = sigm(g[3]) * tanh_f(c) * whr;
#pragma unroll
            for (int off = 1; off < 64; off <<= 1) pp += __shfl_xor(pp, off, 64);
            h = pp;
            int tt = dir ? (TLEN - 1 - t) : t;
            if (lane == 0) h1[((size_t)b * TLEN + tt) * 2 + dir] = h;
        }
        {
            float g[4];
#pragma unroll
            for (int k = 0; k < 4; ++k)
                g[k] = fmaf(whh[k], h, fmaf(wi1[k], xB.y, fmaf(wi0[k], xB.x, bias[k])));
            c = sigm(g[1]) * c + sigm(g[0]) * tanh_f(g[2]);
            float pp = sigm(g[3]) * tanh_f(c) * whr;
#pragma unroll
            for (int off = 1; off < 64; off <<= 1) pp += __shfl_xor(pp, off, 64);
            h = pp;
            int tt = dir ? (TLEN - 2 - t) : (t + 1);
            if (lane == 0) h1[((size_t)b * TLEN + tt) * 2 + dir] = h;
        }
        xA = xC; xB = xD;
    }
}

__global__ __launch_bounds__(256) void mean_kernel(
    const float2* __restrict__ h1, float* __restrict__ out)
{
    int i = blockIdx.x * 256 + threadIdx.x;
    if (i < BATCH * TLEN) {
        float2 v = h1[i];
        out[i] = 0.5f * (v.x + v.y);
    }
}

// ===========================================================================
extern "C" void kernel_launch(void* const* d_in, const int* in_sizes, int n_in,
                              void* d_out, int out_size, void* d_ws, size_t ws_size,
                              hipStream_t stream)
{
    Src s0 = { (const float*)d_in[0], nullptr, nullptr,
               (const int*)d_in[1], (const int*)d_in[2] };
    const float* ccba_W = (const float*)d_in[3];
    const float* ccba_b = (const float*)d_in[4];
    Src s1 = { (const float*)d_in[5], (const int*)d_in[6], (const float*)d_in[7],
               (const int*)d_in[8], (const int*)d_in[9] };
    const float* cdtx_W = (const float*)d_in[10];
    const float* cdtx_b = (const float*)d_in[11];
    Src s2 = { (const float*)d_in[12], (const int*)d_in[13], (const float*)d_in[14],
               (const int*)d_in[15], (const int*)d_in[16] };
    const float* cust_W = (const float*)d_in[17];
    const float* cust_b = (const float*)d_in[18];
    Src s3 = { (const float*)d_in[19], (const int*)d_in[20], (const float*)d_in[21],
               (const int*)d_in[22], (const int*)d_in[23] };
    const float* dp_W = (const float*)d_in[24];
    const float* dp_b = (const float*)d_in[25];
    Src s4 = { (const float*)d_in[26], (const int*)d_in[27], (const float*)d_in[28],
               (const int*)d_in[29], (const int*)d_in[30] };
    const float* remit_W = (const float*)d_in[31];
    const float* remit_b = (const float*)d_in[32];
    const float* Wih0 = (const float*)d_in[33];
    const float* Whh0 = (const float*)d_in[34];
    const float* Whr0 = (const float*)d_in[35];
    const float* bih0 = (const float*)d_in[36];
    const float* bhh0 = (const float*)d_in[37];
    const float* Wih1 = (const float*)d_in[38];
    const float* Whh1 = (const float*)d_in[39];
    const float* Whr1 = (const float*)d_in[40];
    const float* bih1 = (const float*)d_in[41];
    const float* bhh1 = (const float*)d_in[42];
    float* out = (float*)d_out;

    // ---- workspace plan: gpre chunk (NB MiB) | evlist | cnt | h0 | h1 | wp ----
    const size_t MiB = 1048576;
    int NB = 1000, chunks = 1, cap = NEV + 8192;
    size_t lists_b = 0;
    for (int it = 0; it < 6; ++it) {
        chunks = (BATCH + NB - 1) / NB;
        NB = (BATCH + chunks - 1) / chunks;
        cap = NEV / chunks + 8192;
        lists_b = ((size_t)5 * chunks * cap * 4 + 255) & ~(size_t)255;
        size_t need = (size_t)NB * MiB + lists_b + 512 + 4096000 * 2 + 266240 + 1024;
        if (need <= ws_size) break;
        size_t fixed = lists_b + 512 + 4096000 * 2 + 266240 + 1024;
        size_t avail = ws_size > fixed ? ws_size - fixed : MiB;
        int nb_new = (int)(avail / MiB);
        if (nb_new >= NB) nb_new = NB - 1;
        if (nb_new < 2) nb_new = 2;
        NB = nb_new;
    }

    char* p = (char*)d_ws;
    float* gpre  = (float*)p;
    size_t off   = (size_t)NB * MiB;
    int*   evlist = (int*)(p + off);   off += lists_b;
    int*   cnt    = (int*)(p + off);   off += ((size_t)5 * chunks * 4 + 255) & ~(size_t)255;
    float* h0     = (float*)(p + off); off += 4096000;
    float* h1     = (float*)(p + off); off += 4096000;
    float* wp     = (float*)(p + off);

    // ---- one-time per call: composed weights + chunk event lists ----
    compose_kernel<<<130, 512, 0, stream>>>(
        ccba_W, ccba_b, cdtx_W, cdtx_b, cust_W, cust_b,
        dp_W, dp_b, remit_W, remit_b, Wih0, bih0, bhh0, wp);

    hipMemsetAsync(cnt, 0, (size_t)5 * chunks * 4, stream);
    build_lists<<<(5 * NEV + 255) / 256, 256, 0, stream>>>(
        s0, s1, s2, s3, s4, NB, chunks, cap, cnt, evlist);

    // ---- chunked: project gates, then recurrence ----
    for (int ck = 0; ck < chunks; ++ck) {
        const int b0 = ck * NB;
        const int nb = (BATCH - b0) < NB ? (BATCH - b0) : NB;
        project_all<<<dim3(256, 5), 512, 0, stream>>>(
            s0, s1, s2, s3, s4, wp, gpre, cnt, evlist, cap, ck, chunks, b0);
        rec0_chunk<<<(nb * 2 + 3) / 4, 256, 0, stream>>>(
            gpre, Whh0, Whr0, h0, b0, nb);
    }

    lstm1_kernel<<<(BATCH * 2) / 4, 256, 0, stream>>>(
        h0, Wih1, Whh1, Whr1, bih1, bhh1, h1);
    mean_kernel<<<(BATCH * TLEN + 255) / 256, 256, 0, stream>>>(
        (const float2*)h1, out);
}

// Round 5
// 1907.905 us; speedup vs baseline: 2.3508x; 2.3508x over previous
//
#include <hip/hip_runtime.h>
#include <cstdint>
#include <cstddef>

#define TLEN 512
#define BATCH 1000
#define NEV 102400
#define HID 64
#define MAXCH 32
#define SBLK 400   // hist/scatter blocks per source = NEV/256

__device__ __forceinline__ float fast_rcp(float x) {
#if __has_builtin(__builtin_amdgcn_rcpf)
    return __builtin_amdgcn_rcpf(x);
#else
    return 1.0f / x;
#endif
}
__device__ __forceinline__ float sigm(float x) { return fast_rcp(1.0f + __expf(-x)); }
__device__ __forceinline__ float tanh_f(float x) { return fmaf(2.0f, sigm(2.0f * x), -1.0f); }

struct Src {
    const float* num;
    const int*   cat;
    const float* tab;
    const int*   bi;
    const int*   ti;
};

// ---------------------------------------------------------------------------
// compose: W'[row][col], row = per-source [W rows..., bias row], col = Wih0 row.
// ---------------------------------------------------------------------------
__global__ __launch_bounds__(512) void compose_kernel(
    const float* __restrict__ W0, const float* __restrict__ B0,
    const float* __restrict__ W1, const float* __restrict__ B1,
    const float* __restrict__ W2, const float* __restrict__ B2,
    const float* __restrict__ W3, const float* __restrict__ B3,
    const float* __restrict__ W4, const float* __restrict__ B4,
    const float* __restrict__ Wih, const float* __restrict__ bih,
    const float* __restrict__ bhh, float* __restrict__ wp)
{
    const int col = threadIdx.x;   // 0..511 == dir*256 + r == Wih0 row index
    const int row = blockIdx.x;    // 0..129
    const float* srcW; const float* srcB; int base, IND;
    if (row < 9)        { srcW = W0; srcB = B0; base = 0;   IND = 8;  }
    else if (row < 27)  { srcW = W1; srcB = B1; base = 9;   IND = 17; }
    else if (row < 53)  { srcW = W2; srcB = B2; base = 27;  IND = 25; }
    else if (row < 120) { srcW = W3; srcB = B3; base = 53;  IND = 66; }
    else                { srcW = W4; srcB = B4; base = 120; IND = 9;  }
    const int j = row - base;
    const float* xrow = (j < IND) ? (srcW + (size_t)j * 64) : srcB;
    const float* wr = Wih + (size_t)col * 64;
    float acc = 0.0f;
#pragma unroll
    for (int h2 = 0; h2 < 64; ++h2) acc = fmaf(xrow[h2], wr[h2], acc);
    if (j == IND) acc += bih[col] + bhh[col];
    wp[(size_t)row * 512 + col] = acc;
}

// ---------------------------------------------------------------------------
// Counting sort of events into (src, chunk) buckets — no contended atomics.
// ---------------------------------------------------------------------------
__device__ __forceinline__ const int* pick_bi(int src, Src s0, Src s1, Src s2, Src s3, Src s4) {
    return (src == 0) ? s0.bi : (src == 1) ? s1.bi :
           (src == 2) ? s2.bi : (src == 3) ? s3.bi : s4.bi;
}

__global__ __launch_bounds__(256) void hist_kernel(
    Src s0, Src s1, Src s2, Src s3, Src s4,
    int NB, int chunks, int* __restrict__ blockhist)
{
    __shared__ int bins[MAXCH];
    const int g = blockIdx.x;            // 0..5*SBLK-1
    const int src = g / SBLK, blk = g - src * SBLK;
    const int* bi = pick_bi(src, s0, s1, s2, s3, s4);
    if (threadIdx.x < chunks) bins[threadIdx.x] = 0;
    __syncthreads();
    const int e = blk * 256 + threadIdx.x;     // NEV == SBLK*256 exactly
    const int c = bi[e] / NB;
    atomicAdd(&bins[c], 1);                    // LDS atomic, low contention
    __syncthreads();
    if (threadIdx.x < chunks)
        blockhist[(size_t)(src * chunks + threadIdx.x) * SBLK + blk] = bins[threadIdx.x];
}

__global__ __launch_bounds__(512) void scan_kernel(
    int* __restrict__ blockhist, int* __restrict__ cnt)
{
    __shared__ int arr[512];
    const int s = blockIdx.x;            // segment = src*chunks + c
    const int i = threadIdx.x;
    const int v = (i < SBLK) ? blockhist[(size_t)s * SBLK + i] : 0;
    arr[i] = v;
    __syncthreads();
#pragma unroll
    for (int d = 1; d < 512; d <<= 1) {
        int t = (i >= d) ? arr[i - d] : 0;
        __syncthreads();
        arr[i] += t;
        __syncthreads();
    }
    if (i < SBLK) blockhist[(size_t)s * SBLK + i] = arr[i] - v;   // exclusive base
    if (i == 511) cnt[s] = arr[511];                              // segment total
}

__global__ __launch_bounds__(256) void scatter_kernel(
    Src s0, Src s1, Src s2, Src s3, Src s4,
    int NB, int chunks, int cap,
    const int* __restrict__ blockhist, int* __restrict__ evlist)
{
    __shared__ int off[MAXCH];
    const int g = blockIdx.x;
    const int src = g / SBLK, blk = g - src * SBLK;
    const int* bi = pick_bi(src, s0, s1, s2, s3, s4);
    if (threadIdx.x < chunks)
        off[threadIdx.x] = blockhist[(size_t)(src * chunks + threadIdx.x) * SBLK + blk];
    __syncthreads();
    const int e = blk * 256 + threadIdx.x;
    const int c = bi[e] / NB;
    const int slot = atomicAdd(&off[c], 1);    // LDS atomic
    if (slot < cap) evlist[(size_t)(src * chunks + c) * cap + slot] = e;
}

// ---------------------------------------------------------------------------
// project: g_pre[(bi-b0)*T+ti][col] = b'[col] + sum_j x[j]*W'[j][col]
// dense per-(src,chunk) event list, 1-deep prefetch of num/cat (tab chained).
// ---------------------------------------------------------------------------
template<int NNUM, int NCAT>
__device__ __forceinline__ void project_body(
    const Src s, const float* __restrict__ wp, float* __restrict__ gpre,
    const int* __restrict__ list, const int n, const int b0)
{
    constexpr int IND = NCAT * 8 + NNUM;
    constexpr int NC = NCAT > 0 ? NCAT : 1;
    const int col = threadIdx.x;
    float wcol[IND];
#pragma unroll
    for (int j = 0; j < IND; ++j) wcol[j] = wp[(size_t)j * 512 + col];
    const float bcol = wp[(size_t)IND * 512 + col];

    int i = (int)blockIdx.x;
    if (i >= n) return;
    const int stride = (int)gridDim.x;

    int ev = list[i];
    int nbi = s.bi[ev], nti = s.ti[ev];
    int ncat[NC]; float nnum[NNUM ? NNUM : 1];
#pragma unroll
    for (int c = 0; c < NCAT; ++c) ncat[c] = s.cat[ev * NCAT + c];
#pragma unroll
    for (int u = 0; u < NNUM; ++u) nnum[u] = s.num[(size_t)ev * NNUM + u];

    while (true) {
        const int cbi = nbi, cti = nti;
        int ccat[NC]; float cnum[NNUM ? NNUM : 1];
#pragma unroll
        for (int c = 0; c < NCAT; ++c) ccat[c] = ncat[c];
#pragma unroll
        for (int u = 0; u < NNUM; ++u) cnum[u] = nnum[u];

        const int ni = i + stride;
        if (ni < n) {
            ev = list[ni];
            nbi = s.bi[ev]; nti = s.ti[ev];
#pragma unroll
            for (int c = 0; c < NCAT; ++c) ncat[c] = s.cat[ev * NCAT + c];
#pragma unroll
            for (int u = 0; u < NNUM; ++u) nnum[u] = s.num[(size_t)ev * NNUM + u];
        }

        float acc = bcol;
#pragma unroll
        for (int c = 0; c < NCAT; ++c) {
            const float* tr = s.tab + (size_t)ccat[c] * 8;
#pragma unroll
            for (int u = 0; u < 8; ++u)
                acc = fmaf(tr[u], wcol[c * 8 + u], acc);
        }
#pragma unroll
        for (int u = 0; u < NNUM; ++u)
            acc = fmaf(cnum[u], wcol[NCAT * 8 + u], acc);

        gpre[((size_t)(cbi - b0) * TLEN + cti) * 512 + col] = acc;

        i = ni;
        if (i >= n) break;
    }
}

__global__ __launch_bounds__(512) void project_all(
    Src s0, Src s1, Src s2, Src s3, Src s4,
    const float* __restrict__ wp, float* __restrict__ gpre,
    const int* __restrict__ cnt, const int* __restrict__ evlist,
    int cap, int chunkIdx, int chunks, int b0)
{
    const int src = blockIdx.y;
    int n = cnt[src * chunks + chunkIdx];
    if (n > cap) n = cap;
    const int* list = evlist + (size_t)(src * chunks + chunkIdx) * cap;
    switch (src) {
        case 0: project_body<8, 0>(s0, wp,              gpre, list, n, b0); break;
        case 1: project_body<1, 2>(s1, wp + 9 * 512,    gpre, list, n, b0); break;
        case 2: project_body<1, 3>(s2, wp + 27 * 512,   gpre, list, n, b0); break;
        case 3: project_body<2, 8>(s3, wp + 53 * 512,   gpre, list, n, b0); break;
        default: project_body<1, 1>(s4, wp + 120 * 512, gpre, list, n, b0); break;
    }
}

// ---------------------------------------------------------------------------
// rec0: recurrence over precomputed gates for one batch-chunk.
// One wave per (b,dir); lane = cell; 8-step-deep gate prefetch (32 loads
// in flight per wave -> ~16 GB/s/wave, hits the serial compute floor).
// ---------------------------------------------------------------------------
__global__ __launch_bounds__(256) void rec0_chunk(
    const float* __restrict__ gpre, const float* __restrict__ Whh,
    const float* __restrict__ Whr, float* __restrict__ h0,
    int b0, int nb)
{
    const int wv = threadIdx.x >> 6, lane = threadIdx.x & 63;
    const int p = blockIdx.x * 4 + wv;
    if (p >= nb * 2) return;
    const int bl = p >> 1, dir = p & 1;

    float whh4[4];
#pragma unroll
    for (int k = 0; k < 4; ++k) whh4[k] = Whh[dir * 256 + k * 64 + lane];
    const float whr = Whr[dir * HID + lane];

    const float* gb = gpre + (size_t)bl * TLEN * 512 + dir * 256 + lane;
    float* h0p = h0 + (size_t)(b0 + bl) * TLEN * 2 + dir;

    auto addr = [&](int t) -> const float* {
        int tc = t < TLEN ? t : TLEN - 1;         // clamp (value unused past end)
        int tt = dir ? (TLEN - 1 - tc) : tc;
        return gb + (size_t)tt * 512;
    };

    float P[8][4];
#pragma unroll
    for (int d = 0; d < 8; ++d) {
        const float* pa = addr(d);
#pragma unroll
        for (int k = 0; k < 4; ++k) P[d][k] = pa[k * 64];
    }

    float h = 0.0f, c = 0.0f;

    for (int t = 0; t < TLEN; t += 8) {
        float N[8][4];
#pragma unroll
        for (int d = 0; d < 8; ++d) {
            const float* pn = addr(t + 8 + d);
#pragma unroll
            for (int k = 0; k < 4; ++k) N[d][k] = pn[k * 64];
        }
#pragma unroll
        for (int d = 0; d < 8; ++d) {
            float gi = fmaf(whh4[0], h, P[d][0]);
            float gf = fmaf(whh4[1], h, P[d][1]);
            float gg = fmaf(whh4[2], h, P[d][2]);
            float go = fmaf(whh4[3], h, P[d][3]);
            c = sigm(gf) * c + sigm(gi) * tanh_f(gg);
            float pp = sigm(go) * tanh_f(c) * whr;
#pragma unroll
            for (int off = 1; off < 64; off <<= 1) pp += __shfl_xor(pp, off, 64);
            h = pp;
            const int tt = dir ? (TLEN - 1 - (t + d)) : (t + d);
            if (lane == 0) h0p[(size_t)tt * 2] = h;
        }
#pragma unroll
        for (int d = 0; d < 8; ++d)
#pragma unroll
            for (int k = 0; k < 4; ++k) P[d][k] = N[d][k];
    }
}

// ---------------------------------------------------------------------------
// LSTM layer 1 (insz=2), one wave per (b,dir), 2-step x prefetch.
// ---------------------------------------------------------------------------
__global__ __launch_bounds__(256) void lstm1_kernel(
    const float* __restrict__ h0, const float* __restrict__ Wih,
    const float* __restrict__ Whh, const float* __restrict__ Whr,
    const float* __restrict__ bih, const float* __restrict__ bhh,
    float* __restrict__ h1)
{
    int w = threadIdx.x >> 6, lane = threadIdx.x & 63;
    int p = blockIdx.x * 4 + w;
    int b = p >> 1, dir = p & 1;

    float wi0[4], wi1[4], whh[4], bias[4];
#pragma unroll
    for (int k = 0; k < 4; ++k) {
        int r = k * 64 + lane;
        wi0[k] = Wih[(size_t)(dir * 256 + r) * 2 + 0];
        wi1[k] = Wih[(size_t)(dir * 256 + r) * 2 + 1];
        whh[k] = Whh[dir * 256 + r];
        bias[k] = bih[dir * 256 + r] + bhh[dir * 256 + r];
    }
    float whr = Whr[dir * HID + lane];
    float h = 0.0f, c = 0.0f;
    const float* hb = h0 + (size_t)b * TLEN * 2;

    auto xat = [&](int t) -> float2 {
        int tc = t < TLEN ? t : TLEN - 1;
        int tt = dir ? (TLEN - 1 - tc) : tc;
        return *(const float2*)(hb + (size_t)tt * 2);
    };

    float2 xA = xat(0), xB = xat(1);
    for (int t = 0; t < TLEN; t += 2) {
        float2 xC = xat(t + 2), xD = xat(t + 3);
        {
            float g[4];
#pragma unroll
            for (int k = 0; k < 4; ++k)
                g[k] = fmaf(whh[k], h, fmaf(wi1[k], xA.y, fmaf(wi0[k], xA.x, bias[k])));
            c = sigm(g[1]) * c + sigm(g[0]) * tanh_f(g[2]);
            float pp = sigm(g[3]) * tanh_f(c) * whr;
#pragma unroll
            for (int off = 1; off < 64; off <<= 1) pp += __shfl_xor(pp, off, 64);
            h = pp;
            int tt = dir ? (TLEN - 1 - t) : t;
            if (lane == 0) h1[((size_t)b * TLEN + tt) * 2 + dir] = h;
        }
        {
            float g[4];
#pragma unroll
            for (int k = 0; k < 4; ++k)
                g[k] = fmaf(whh[k], h, fmaf(wi1[k], xB.y, fmaf(wi0[k], xB.x, bias[k])));
            c = sigm(g[1]) * c + sigm(g[0]) * tanh_f(g[2]);
            float pp = sigm(g[3]) * tanh_f(c) * whr;
#pragma unroll
            for (int off = 1; off < 64; off <<= 1) pp += __shfl_xor(pp, off, 64);
            h = pp;
            int tt = dir ? (TLEN - 2 - t) : (t + 1);
            if (lane == 0) h1[((size_t)b * TLEN + tt) * 2 + dir] = h;
        }
        xA = xC; xB = xD;
    }
}

__global__ __launch_bounds__(256) void mean_kernel(
    const float2* __restrict__ h1, float* __restrict__ out)
{
    int i = blockIdx.x * 256 + threadIdx.x;
    if (i < BATCH * TLEN) {
        float2 v = h1[i];
        out[i] = 0.5f * (v.x + v.y);
    }
}

// ===========================================================================
extern "C" void kernel_launch(void* const* d_in, const int* in_sizes, int n_in,
                              void* d_out, int out_size, void* d_ws, size_t ws_size,
                              hipStream_t stream)
{
    Src s0 = { (const float*)d_in[0], nullptr, nullptr,
               (const int*)d_in[1], (const int*)d_in[2] };
    const float* ccba_W = (const float*)d_in[3];
    const float* ccba_b = (const float*)d_in[4];
    Src s1 = { (const float*)d_in[5], (const int*)d_in[6], (const float*)d_in[7],
               (const int*)d_in[8], (const int*)d_in[9] };
    const float* cdtx_W = (const float*)d_in[10];
    const float* cdtx_b = (const float*)d_in[11];
    Src s2 = { (const float*)d_in[12], (const int*)d_in[13], (const float*)d_in[14],
               (const int*)d_in[15], (const int*)d_in[16] };
    const float* cust_W = (const float*)d_in[17];
    const float* cust_b = (const float*)d_in[18];
    Src s3 = { (const float*)d_in[19], (const int*)d_in[20], (const float*)d_in[21],
               (const int*)d_in[22], (const int*)d_in[23] };
    const float* dp_W = (const float*)d_in[24];
    const float* dp_b = (const float*)d_in[25];
    Src s4 = { (const float*)d_in[26], (const int*)d_in[27], (const float*)d_in[28],
               (const int*)d_in[29], (const int*)d_in[30] };
    const float* remit_W = (const float*)d_in[31];
    const float* remit_b = (const float*)d_in[32];
    const float* Wih0 = (const float*)d_in[33];
    const float* Whh0 = (const float*)d_in[34];
    const float* Whr0 = (const float*)d_in[35];
    const float* bih0 = (const float*)d_in[36];
    const float* bhh0 = (const float*)d_in[37];
    const float* Wih1 = (const float*)d_in[38];
    const float* Whh1 = (const float*)d_in[39];
    const float* Whr1 = (const float*)d_in[40];
    const float* bih1 = (const float*)d_in[41];
    const float* bhh1 = (const float*)d_in[42];
    float* out = (float*)d_out;

    // ---- workspace plan: minimize chunk count (largest NB that fits) ----
    const size_t MiB = 1048576;
    int chunks = 0, NB = 0, cap = 0;
    size_t lists_b = 0, bh_b = 0;
    for (int ch = 1; ch <= MAXCH; ++ch) {
        int nb = (BATCH + ch - 1) / ch;
        int cp = (ch == 1) ? NEV : (NEV / ch + 8192);
        size_t lb = ((size_t)5 * ch * cp * 4 + 255) & ~(size_t)255;
        size_t bb = ((size_t)5 * ch * SBLK * 4 + 255) & ~(size_t)255;
        size_t need = (size_t)nb * MiB + lb + bb + 512
                      + (size_t)4096000 * 2 + 266240 + 4096;
        if (need <= ws_size) {
            chunks = ch; NB = nb; cap = cp; lists_b = lb; bh_b = bb;
            break;
        }
    }
    if (chunks == 0) { chunks = MAXCH; NB = (BATCH + MAXCH - 1) / MAXCH;
                       cap = NEV / MAXCH + 8192;
                       lists_b = ((size_t)5 * chunks * cap * 4 + 255) & ~(size_t)255;
                       bh_b = ((size_t)5 * chunks * SBLK * 4 + 255) & ~(size_t)255; }

    char* p = (char*)d_ws;
    float* gpre      = (float*)p;
    size_t off       = (size_t)NB * MiB;
    int*   evlist    = (int*)(p + off);   off += lists_b;
    int*   blockhist = (int*)(p + off);   off += bh_b;
    int*   cnt       = (int*)(p + off);   off += 512;
    float* h0        = (float*)(p + off); off += 4096000;
    float* h1        = (float*)(p + off); off += 4096000;
    float* wp        = (float*)(p + off);

    // ---- one-time per call ----
    compose_kernel<<<130, 512, 0, stream>>>(
        ccba_W, ccba_b, cdtx_W, cdtx_b, cust_W, cust_b,
        dp_W, dp_b, remit_W, remit_b, Wih0, bih0, bhh0, wp);

    hist_kernel<<<5 * SBLK, 256, 0, stream>>>(s0, s1, s2, s3, s4, NB, chunks, blockhist);
    scan_kernel<<<5 * chunks, 512, 0, stream>>>(blockhist, cnt);
    scatter_kernel<<<5 * SBLK, 256, 0, stream>>>(s0, s1, s2, s3, s4, NB, chunks, cap,
                                                 blockhist, evlist);

    // ---- chunked: project gates, then recurrence ----
    for (int ck = 0; ck < chunks; ++ck) {
        const int b0 = ck * NB;
        const int nb = (BATCH - b0) < NB ? (BATCH - b0) : NB;
        project_all<<<dim3(512, 5), 512, 0, stream>>>(
            s0, s1, s2, s3, s4, wp, gpre, cnt, evlist, cap, ck, chunks, b0);
        rec0_chunk<<<(nb * 2 + 3) / 4, 256, 0, stream>>>(
            gpre, Whh0, Whr0, h0, b0, nb);
    }

    lstm1_kernel<<<(BATCH * 2) / 4, 256, 0, stream>>>(
        h0, Wih1, Whh1, Whr1, bih1, bhh1, h1);
    mean_kernel<<<(BATCH * TLEN + 255) / 256, 256, 0, stream>>>(
        (const float2*)h1, out);
}

// Round 6
// 1667.314 us; speedup vs baseline: 2.6900x; 1.1443x over previous
//
#include <hip/hip_runtime.h>
#include <cstdint>
#include <cstddef>

#define TLEN 512
#define BATCH 1000
#define NEV 102400
#define HID 64
#define MAXCH 64
#define SBLK 400   // hist/scatter blocks per source = NEV/256

__device__ __forceinline__ float fast_rcp(float x) {
#if __has_builtin(__builtin_amdgcn_rcpf)
    return __builtin_amdgcn_rcpf(x);
#else
    return 1.0f / x;
#endif
}
__device__ __forceinline__ float sigm(float x) { return fast_rcp(1.0f + __expf(-x)); }
__device__ __forceinline__ float tanh_f(float x) { return fmaf(2.0f, sigm(2.0f * x), -1.0f); }

// ---- wave-wide sum via DPP (row_shr 1/2/4/8 + row_bcast 15/31), result
// broadcast to all lanes through v_readlane(63) -> SGPR. ~6 VALU-latency ops
// vs 6 x ds_bpermute for __shfl_xor.
template<int CTRL>
__device__ __forceinline__ float dpp_add(float x) {
    union { float f; int i; } u, v;
    u.f = x;
    v.i = __builtin_amdgcn_update_dpp(0, u.i, CTRL, 0xF, 0xF, true);
    return x + v.f;
}
__device__ __forceinline__ float wave_sum_all(float x) {
    x = dpp_add<0x111>(x);   // row_shr:1
    x = dpp_add<0x112>(x);   // row_shr:2
    x = dpp_add<0x114>(x);   // row_shr:4
    x = dpp_add<0x118>(x);   // row_shr:8
    x = dpp_add<0x142>(x);   // row_bcast:15
    x = dpp_add<0x143>(x);   // row_bcast:31  -> lane 63 = total
    union { float f; int i; } u; u.f = x;
    u.i = __builtin_amdgcn_readlane(u.i, 63);
    return u.f;
}

struct Src {
    const float* num;
    const int*   cat;
    const float* tab;
    const int*   bi;
    const int*   ti;
};

// ---------------------------------------------------------------------------
// compose: W'[row][col], row = per-source [W rows..., bias row], col = Wih0 row.
// ---------------------------------------------------------------------------
__global__ __launch_bounds__(512) void compose_kernel(
    const float* __restrict__ W0, const float* __restrict__ B0,
    const float* __restrict__ W1, const float* __restrict__ B1,
    const float* __restrict__ W2, const float* __restrict__ B2,
    const float* __restrict__ W3, const float* __restrict__ B3,
    const float* __restrict__ W4, const float* __restrict__ B4,
    const float* __restrict__ Wih, const float* __restrict__ bih,
    const float* __restrict__ bhh, float* __restrict__ wp)
{
    const int col = threadIdx.x;   // 0..511 == dir*256 + r == Wih0 row index
    const int row = blockIdx.x;    // 0..129
    const float* srcW; const float* srcB; int base, IND;
    if (row < 9)        { srcW = W0; srcB = B0; base = 0;   IND = 8;  }
    else if (row < 27)  { srcW = W1; srcB = B1; base = 9;   IND = 17; }
    else if (row < 53)  { srcW = W2; srcB = B2; base = 27;  IND = 25; }
    else if (row < 120) { srcW = W3; srcB = B3; base = 53;  IND = 66; }
    else                { srcW = W4; srcB = B4; base = 120; IND = 9;  }
    const int j = row - base;
    const float* xrow = (j < IND) ? (srcW + (size_t)j * 64) : srcB;
    const float* wr = Wih + (size_t)col * 64;
    float acc = 0.0f;
#pragma unroll
    for (int h2 = 0; h2 < 64; ++h2) acc = fmaf(xrow[h2], wr[h2], acc);
    if (j == IND) acc += bih[col] + bhh[col];
    wp[(size_t)row * 512 + col] = acc;
}

// ---------------------------------------------------------------------------
// Counting sort of events into (src, chunk) buckets — no contended atomics.
// ---------------------------------------------------------------------------
__device__ __forceinline__ const int* pick_bi(int src, Src s0, Src s1, Src s2, Src s3, Src s4) {
    return (src == 0) ? s0.bi : (src == 1) ? s1.bi :
           (src == 2) ? s2.bi : (src == 3) ? s3.bi : s4.bi;
}

__global__ __launch_bounds__(256) void hist_kernel(
    Src s0, Src s1, Src s2, Src s3, Src s4,
    int NB, int chunks, int* __restrict__ blockhist)
{
    __shared__ int bins[MAXCH];
    const int g = blockIdx.x;            // 0..5*SBLK-1
    const int src = g / SBLK, blk = g - src * SBLK;
    const int* bi = pick_bi(src, s0, s1, s2, s3, s4);
    if (threadIdx.x < chunks) bins[threadIdx.x] = 0;
    __syncthreads();
    const int e = blk * 256 + threadIdx.x;     // NEV == SBLK*256 exactly
    const int c = bi[e] / NB;
    atomicAdd(&bins[c], 1);                    // LDS atomic, low contention
    __syncthreads();
    if (threadIdx.x < chunks)
        blockhist[(size_t)(src * chunks + threadIdx.x) * SBLK + blk] = bins[threadIdx.x];
}

__global__ __launch_bounds__(512) void scan_kernel(
    int* __restrict__ blockhist, int* __restrict__ cnt)
{
    __shared__ int arr[512];
    const int s = blockIdx.x;            // segment = src*chunks + c
    const int i = threadIdx.x;
    const int v = (i < SBLK) ? blockhist[(size_t)s * SBLK + i] : 0;
    arr[i] = v;
    __syncthreads();
#pragma unroll
    for (int d = 1; d < 512; d <<= 1) {
        int t = (i >= d) ? arr[i - d] : 0;
        __syncthreads();
        arr[i] += t;
        __syncthreads();
    }
    if (i < SBLK) blockhist[(size_t)s * SBLK + i] = arr[i] - v;   // exclusive base
    if (i == 511) cnt[s] = arr[511];                              // segment total
}

__global__ __launch_bounds__(256) void scatter_kernel(
    Src s0, Src s1, Src s2, Src s3, Src s4,
    int NB, int chunks, int cap,
    const int* __restrict__ blockhist, int* __restrict__ evlist)
{
    __shared__ int off[MAXCH];
    const int g = blockIdx.x;
    const int src = g / SBLK, blk = g - src * SBLK;
    const int* bi = pick_bi(src, s0, s1, s2, s3, s4);
    if (threadIdx.x < chunks)
        off[threadIdx.x] = blockhist[(size_t)(src * chunks + threadIdx.x) * SBLK + blk];
    __syncthreads();
    const int e = blk * 256 + threadIdx.x;
    const int c = bi[e] / NB;
    const int slot = atomicAdd(&off[c], 1);    // LDS atomic
    if (slot < cap) evlist[(size_t)(src * chunks + c) * cap + slot] = e;
}

// ---------------------------------------------------------------------------
// project body: g_pre[(bi-b0)*T+ti][col] = b'[col] + sum_j x[j]*W'[j][col]
// dense per-(src,chunk) event list, 1-deep prefetch of num/cat.
// ---------------------------------------------------------------------------
template<int NNUM, int NCAT>
__device__ __forceinline__ void project_body(
    const Src s, const float* __restrict__ wp, float* __restrict__ gpre,
    const int* __restrict__ list, const int n, const int b0,
    const int i0, const int stride)
{
    constexpr int IND = NCAT * 8 + NNUM;
    constexpr int NC = NCAT > 0 ? NCAT : 1;
    const int col = threadIdx.x;
    float wcol[IND];
#pragma unroll
    for (int j = 0; j < IND; ++j) wcol[j] = wp[(size_t)j * 512 + col];
    const float bcol = wp[(size_t)IND * 512 + col];

    int i = i0;
    if (i >= n) return;

    int ev = list[i];
    int nbi = s.bi[ev], nti = s.ti[ev];
    int ncat[NC]; float nnum[NNUM ? NNUM : 1];
#pragma unroll
    for (int c = 0; c < NCAT; ++c) ncat[c] = s.cat[ev * NCAT + c];
#pragma unroll
    for (int u = 0; u < NNUM; ++u) nnum[u] = s.num[(size_t)ev * NNUM + u];

    while (true) {
        const int cbi = nbi, cti = nti;
        int ccat[NC]; float cnum[NNUM ? NNUM : 1];
#pragma unroll
        for (int c = 0; c < NCAT; ++c) ccat[c] = ncat[c];
#pragma unroll
        for (int u = 0; u < NNUM; ++u) cnum[u] = nnum[u];

        const int ni = i + stride;
        if (ni < n) {
            ev = list[ni];
            nbi = s.bi[ev]; nti = s.ti[ev];
#pragma unroll
            for (int c = 0; c < NCAT; ++c) ncat[c] = s.cat[ev * NCAT + c];
#pragma unroll
            for (int u = 0; u < NNUM; ++u) nnum[u] = s.num[(size_t)ev * NNUM + u];
        }

        float acc = bcol;
#pragma unroll
        for (int c = 0; c < NCAT; ++c) {
            const float* tr = s.tab + (size_t)ccat[c] * 8;
#pragma unroll
            for (int u = 0; u < 8; ++u)
                acc = fmaf(tr[u], wcol[c * 8 + u], acc);
        }
#pragma unroll
        for (int u = 0; u < NNUM; ++u)
            acc = fmaf(cnum[u], wcol[NCAT * 8 + u], acc);

        gpre[((size_t)(cbi - b0) * TLEN + cti) * 512 + col] = acc;

        i = ni;
        if (i >= n) break;
    }
}

// ---------------------------------------------------------------------------
// rec0 wave body: recurrence over precomputed gates, one wave per (b,dir).
// lane = cell; 8-step-deep gate prefetch; DPP reduce.
// ---------------------------------------------------------------------------
__device__ __forceinline__ void rec0_wave(
    const float* __restrict__ gpre, const float* __restrict__ Whh,
    const float* __restrict__ Whr, float* __restrict__ h0,
    int b0, int nb, int pair)
{
    if (pair >= nb * 2) return;               // wave-uniform guard
    const int lane = threadIdx.x & 63;
    const int bl = pair >> 1, dir = pair & 1;

    float whh4[4];
#pragma unroll
    for (int k = 0; k < 4; ++k) whh4[k] = Whh[dir * 256 + k * 64 + lane];
    const float whr = Whr[dir * HID + lane];

    const float* gb = gpre + (size_t)bl * TLEN * 512 + dir * 256 + lane;
    float* h0p = h0 + (size_t)(b0 + bl) * TLEN * 2 + dir;

    auto addr = [&](int t) -> const float* {
        int tc = t < TLEN ? t : TLEN - 1;     // clamp (value unused past end)
        int tt = dir ? (TLEN - 1 - tc) : tc;
        return gb + (size_t)tt * 512;
    };

    float P[8][4];
#pragma unroll
    for (int d = 0; d < 8; ++d) {
        const float* pa = addr(d);
#pragma unroll
        for (int k = 0; k < 4; ++k) P[d][k] = pa[k * 64];
    }

    float h = 0.0f, c = 0.0f;

    for (int t = 0; t < TLEN; t += 8) {
        float N[8][4];
#pragma unroll
        for (int d = 0; d < 8; ++d) {
            const float* pn = addr(t + 8 + d);
#pragma unroll
            for (int k = 0; k < 4; ++k) N[d][k] = pn[k * 64];
        }
#pragma unroll
        for (int d = 0; d < 8; ++d) {
            float gi = fmaf(whh4[0], h, P[d][0]);
            float gf = fmaf(whh4[1], h, P[d][1]);
            float gg = fmaf(whh4[2], h, P[d][2]);
            float go = fmaf(whh4[3], h, P[d][3]);
            c = sigm(gf) * c + sigm(gi) * tanh_f(gg);
            float pp = sigm(go) * tanh_f(c) * whr;
            h = wave_sum_all(pp);
            const int tt = dir ? (TLEN - 1 - (t + d)) : (t + d);
            if (lane == 0) h0p[(size_t)tt * 2] = h;
        }
#pragma unroll
        for (int d = 0; d < 8; ++d)
#pragma unroll
            for (int k = 0; k < 4; ++k) P[d][k] = N[d][k];
    }
}

// ---------------------------------------------------------------------------
// fused pipeline stage: blocks [0, rblk) run rec0 for chunk ckr (buffer grec);
// blocks [rblk, rblk + 5*pb) run project for chunk ckp (buffer gproj).
// rec blocks first so the latency-bound recurrence dispatches earliest.
// ---------------------------------------------------------------------------
__global__ __launch_bounds__(512) void fused_stage(
    Src s0, Src s1, Src s2, Src s3, Src s4,
    const float* __restrict__ wp,
    float* __restrict__ gproj, const float* __restrict__ grec,
    const int* __restrict__ cnt, const int* __restrict__ evlist,
    int cap, int chunks, int ckp, int b0p, int pb,
    const float* __restrict__ Whh, const float* __restrict__ Whr,
    float* __restrict__ h0, int b0r, int nbr, int rblk)
{
    if ((int)blockIdx.x < rblk) {
        const int pair = blockIdx.x * 8 + (threadIdx.x >> 6);
        rec0_wave(grec, Whh, Whr, h0, b0r, nbr, pair);
        return;
    }
    const int g = blockIdx.x - rblk;
    const int src = g / pb;
    const int i0 = g - src * pb;
    int n = cnt[src * chunks + ckp];
    if (n > cap) n = cap;
    const int* list = evlist + (size_t)(src * chunks + ckp) * cap;
    switch (src) {
        case 0: project_body<8, 0>(s0, wp,              gproj, list, n, b0p, i0, pb); break;
        case 1: project_body<1, 2>(s1, wp + 9 * 512,    gproj, list, n, b0p, i0, pb); break;
        case 2: project_body<1, 3>(s2, wp + 27 * 512,   gproj, list, n, b0p, i0, pb); break;
        case 3: project_body<2, 8>(s3, wp + 53 * 512,   gproj, list, n, b0p, i0, pb); break;
        default: project_body<1, 1>(s4, wp + 120 * 512, gproj, list, n, b0p, i0, pb); break;
    }
}

// ---------------------------------------------------------------------------
// LSTM layer 1 (insz=2), one wave per (b,dir), 8-step x prefetch, DPP reduce.
// ---------------------------------------------------------------------------
__global__ __launch_bounds__(256) void lstm1_kernel(
    const float* __restrict__ h0, const float* __restrict__ Wih,
    const float* __restrict__ Whh, const float* __restrict__ Whr,
    const float* __restrict__ bih, const float* __restrict__ bhh,
    float* __restrict__ h1)
{
    int w = threadIdx.x >> 6, lane = threadIdx.x & 63;
    int p = blockIdx.x * 4 + w;
    int b = p >> 1, dir = p & 1;

    float wi0[4], wi1[4], whh[4], bias[4];
#pragma unroll
    for (int k = 0; k < 4; ++k) {
        int r = k * 64 + lane;
        wi0[k] = Wih[(size_t)(dir * 256 + r) * 2 + 0];
        wi1[k] = Wih[(size_t)(dir * 256 + r) * 2 + 1];
        whh[k] = Whh[dir * 256 + r];
        bias[k] = bih[dir * 256 + r] + bhh[dir * 256 + r];
    }
    float whr = Whr[dir * HID + lane];
    float h = 0.0f, c = 0.0f;
    const float* hb = h0 + (size_t)b * TLEN * 2;

    auto xat = [&](int t) -> float2 {
        int tc = t < TLEN ? t : TLEN - 1;
        int tt = dir ? (TLEN - 1 - tc) : tc;
        return *(const float2*)(hb + (size_t)tt * 2);
    };

    float2 X[8];
#pragma unroll
    for (int d = 0; d < 8; ++d) X[d] = xat(d);

    for (int t = 0; t < TLEN; t += 8) {
        float2 N[8];
#pragma unroll
        for (int d = 0; d < 8; ++d) N[d] = xat(t + 8 + d);
#pragma unroll
        for (int d = 0; d < 8; ++d) {
            float g[4];
#pragma unroll
            for (int k = 0; k < 4; ++k)
                g[k] = fmaf(whh[k], h, fmaf(wi1[k], X[d].y, fmaf(wi0[k], X[d].x, bias[k])));
            c = sigm(g[1]) * c + sigm(g[0]) * tanh_f(g[2]);
            float pp = sigm(g[3]) * tanh_f(c) * whr;
            h = wave_sum_all(pp);
            int tt = dir ? (TLEN - 1 - (t + d)) : (t + d);
            if (lane == 0) h1[((size_t)b * TLEN + tt) * 2 + dir] = h;
        }
#pragma unroll
        for (int d = 0; d < 8; ++d) X[d] = N[d];
    }
}

__global__ __launch_bounds__(256) void mean_kernel(
    const float2* __restrict__ h1, float* __restrict__ out)
{
    int i = blockIdx.x * 256 + threadIdx.x;
    if (i < BATCH * TLEN) {
        float2 v = h1[i];
        out[i] = 0.5f * (v.x + v.y);
    }
}

// ===========================================================================
extern "C" void kernel_launch(void* const* d_in, const int* in_sizes, int n_in,
                              void* d_out, int out_size, void* d_ws, size_t ws_size,
                              hipStream_t stream)
{
    Src s0 = { (const float*)d_in[0], nullptr, nullptr,
               (const int*)d_in[1], (const int*)d_in[2] };
    const float* ccba_W = (const float*)d_in[3];
    const float* ccba_b = (const float*)d_in[4];
    Src s1 = { (const float*)d_in[5], (const int*)d_in[6], (const float*)d_in[7],
               (const int*)d_in[8], (const int*)d_in[9] };
    const float* cdtx_W = (const float*)d_in[10];
    const float* cdtx_b = (const float*)d_in[11];
    Src s2 = { (const float*)d_in[12], (const int*)d_in[13], (const float*)d_in[14],
               (const int*)d_in[15], (const int*)d_in[16] };
    const float* cust_W = (const float*)d_in[17];
    const float* cust_b = (const float*)d_in[18];
    Src s3 = { (const float*)d_in[19], (const int*)d_in[20], (const float*)d_in[21],
               (const int*)d_in[22], (const int*)d_in[23] };
    const float* dp_W = (const float*)d_in[24];
    const float* dp_b = (const float*)d_in[25];
    Src s4 = { (const float*)d_in[26], (const int*)d_in[27], (const float*)d_in[28],
               (const int*)d_in[29], (const int*)d_in[30] };
    const float* remit_W = (const float*)d_in[31];
    const float* remit_b = (const float*)d_in[32];
    const float* Wih0 = (const float*)d_in[33];
    const float* Whh0 = (const float*)d_in[34];
    const float* Whr0 = (const float*)d_in[35];
    const float* bih0 = (const float*)d_in[36];
    const float* bhh0 = (const float*)d_in[37];
    const float* Wih1 = (const float*)d_in[38];
    const float* Whh1 = (const float*)d_in[39];
    const float* Whr1 = (const float*)d_in[40];
    const float* bih1 = (const float*)d_in[41];
    const float* bhh1 = (const float*)d_in[42];
    float* out = (float*)d_out;

    // ---- workspace plan: two ping-pong gpre buffers (NB MiB each) ----
    const size_t MiB = 1048576;
    int chunks = 0, NB = 0, cap = 0;
    size_t lists_b = 0, bh_b = 0;
    for (int ch = 2; ch <= MAXCH; ++ch) {
        int nb = (BATCH + ch - 1) / ch;
        int cp = nb * 512;   // hard bound: events <= positions per chunk
        size_t lb = ((size_t)5 * ch * cp * 4 + 255) & ~(size_t)255;
        size_t bb = ((size_t)5 * ch * SBLK * 4 + 255) & ~(size_t)255;
        size_t need = 2 * (size_t)nb * MiB + lb + bb + 512
                      + (size_t)4096000 * 2 + 266240 + 4096;
        if (need <= ws_size) { chunks = ch; NB = nb; cap = cp; lists_b = lb; bh_b = bb; break; }
    }
    if (chunks == 0) {
        chunks = MAXCH; NB = (BATCH + MAXCH - 1) / MAXCH; cap = NB * 512;
        lists_b = ((size_t)5 * chunks * cap * 4 + 255) & ~(size_t)255;
        bh_b = ((size_t)5 * chunks * SBLK * 4 + 255) & ~(size_t)255;
    }

    char* p = (char*)d_ws;
    float* bufs[2] = { (float*)p, (float*)(p + (size_t)NB * MiB) };
    size_t off = 2 * (size_t)NB * MiB;
    int*   evlist    = (int*)(p + off);   off += lists_b;
    int*   blockhist = (int*)(p + off);   off += bh_b;
    int*   cnt       = (int*)(p + off);   off += 512;
    float* h0        = (float*)(p + off); off += 4096000;
    float* h1        = (float*)(p + off); off += 4096000;
    float* wp        = (float*)(p + off);

    // ---- one-time per call ----
    compose_kernel<<<130, 512, 0, stream>>>(
        ccba_W, ccba_b, cdtx_W, cdtx_b, cust_W, cust_b,
        dp_W, dp_b, remit_W, remit_b, Wih0, bih0, bhh0, wp);

    hist_kernel<<<5 * SBLK, 256, 0, stream>>>(s0, s1, s2, s3, s4, NB, chunks, blockhist);
    scan_kernel<<<5 * chunks, 512, 0, stream>>>(blockhist, cnt);
    scatter_kernel<<<5 * SBLK, 256, 0, stream>>>(s0, s1, s2, s3, s4, NB, chunks, cap,
                                                 blockhist, evlist);

    // ---- software-pipelined: stage st = project(st) + rec0(st-1) ----
    const int PB = 256;   // project blocks per source
    for (int st = 0; st <= chunks; ++st) {
        const int ckp = st, ckr = st - 1;
        const int pb = (ckp < chunks) ? PB : 0;
        int b0r = 0, nbr = 0;
        if (ckr >= 0) {
            b0r = ckr * NB;
            nbr = (BATCH - b0r) < NB ? (BATCH - b0r) : NB;
        }
        const int rblk = (nbr * 2 + 7) / 8;
        const int b0p = ckp * NB;
        const int grid = rblk + 5 * pb;
        fused_stage<<<grid, 512, 0, stream>>>(
            s0, s1, s2, s3, s4, wp,
            bufs[ckp & 1], bufs[ckr >= 0 ? (ckr & 1) : 0],
            cnt, evlist, cap, chunks,
            (ckp < chunks) ? ckp : 0, b0p, pb,
            Whh0, Whr0, h0, b0r, nbr, rblk);
    }

    lstm1_kernel<<<(BATCH * 2) / 4, 256, 0, stream>>>(
        h0, Wih1, Whh1, Whr1, bih1, bhh1, h1);
    mean_kernel<<<(BATCH * TLEN + 255) / 256, 256, 0, stream>>>(
        (const float2*)h1, out);
}